// Round 8
// baseline (1611.540 us; speedup 1.0000x reference)
//
#include <hip/hip_runtime.h>
#include <hip/hip_bf16.h>
#include <cstdint>

// ---------------------------------------------------------------------------
// LSTM  B=64 T=512 I=512 H=512
// Phase 0: convert/transpose inputs -> bf16, W_cat^T bf16, b_cat f32,
//          U pre-swizzled into MFMA B-fragment order.
// Phase 1: x_proj GEMM bf16 MFMA, bias folded, output consumer-swizzled.
// Phase 2: persistent recurrence, 64 WGs = 4 batch-groups x 16 hidden-slices.
//          U slice in registers. h exchanged via TAGGED u64 words (hi32 = tag
//          t+1, lo32 = packed bf16 col-pair), relaxed agent atomics (data IS
//          the flag). Single 16-word coalesced poll (R4-proven).
//          NEW vs R7: (a) barriers are LGKM-ONLY (s_waitcnt lgkmcnt(0) +
//          s_barrier builtins) — __syncthreads' vmcnt(0) drain of xp loads &
//          publish stores is removed from the serial chain. Safe because the
//          barriers only order LDS traffic; h-read-before-publish ordering
//          comes from the tag check (values consumed into registers before
//          staging). (b) xp is prefetched ONE STEP AHEAD into registers
//          (issued after the MFMA block), so its ~1200cyc HBM miss retires
//          off the critical path instead of serializing before the poll
//          check (vmcnt retires in issue order).
// Column convention: c = h_unit*4 + gate   (gate: 0=i,1=f,2=o,3=c)
// ---------------------------------------------------------------------------

typedef __bf16 bf16;
typedef __bf16 bf16x8 __attribute__((ext_vector_type(8)));
typedef float floatx4 __attribute__((ext_vector_type(4)));
typedef uint64_t u64;
typedef uint32_t u32;

#define T_STEPS 512

// ws layout (bytes)
#define XP_OFF     0ull                        // bf16 [T*B*2048] swizzled = 128 MB
#define XBF_OFF    134217728ull                // bf16 [T*B][512]   = 32 MB
#define WCT_OFF    167772160ull                // bf16 [2048][512]  = 2 MB
#define USW_OFF    169869312ull                // bf16 swizzled U B-frags = 2 MB
#define BCAT_OFF   171966464ull                // f32  [2048]
#define HBUF_OFF   171974656ull                // u64 [2][4][16][256] = 256 KB

__device__ inline u32 pack_bf16x2(float a, float b) {
    union { __bf16 h[2]; u32 u; } cv;
    cv.h[0] = (__bf16)a; cv.h[1] = (__bf16)b;
    return cv.u;
}
__device__ inline float bf_lo(u32 w) { return __builtin_bit_cast(float, w << 16); }
__device__ inline float bf_hi(u32 w) { return __builtin_bit_cast(float, w & 0xffff0000u); }

// barrier that waits only LDS (lgkmcnt(0)); global loads/stores stay in flight.
// simm16: vmcnt lo[3:0]=0xF, expcnt[6:4]=7, lgkmcnt[11:8]=0, vmcnt hi[15:14]=3
__device__ inline void lgkm_barrier() {
    __atomic_signal_fence(__ATOMIC_SEQ_CST);
    __builtin_amdgcn_s_waitcnt(0xc07f);
    __builtin_amdgcn_s_barrier();
    __atomic_signal_fence(__ATOMIC_SEQ_CST);
}

// ---------------- K0a: inputs f32 [B][T][I] -> x_bf bf16 in row order (t*64+b)
__global__ void k0a_convert(const float* __restrict__ in, bf16* __restrict__ xbf) {
    int o = blockIdx.x * 256 + threadIdx.x;
    int k = o & 511;
    int r = o >> 9;
    int t = r >> 6, b = r & 63;
    xbf[o] = (bf16)in[(b * 512 + t) * 512 + k];
}

// ---------------- K0b: W_cat^T[c][k] bf16 (c = h*4+gate) and b_cat f32
__global__ void k0b_wcat(const float* __restrict__ Wi, const float* __restrict__ Wf,
                         const float* __restrict__ Wo, const float* __restrict__ Wc,
                         const float* __restrict__ bi, const float* __restrict__ bfv,
                         const float* __restrict__ bo, const float* __restrict__ bc,
                         bf16* __restrict__ wct, float* __restrict__ bcat) {
    int o = blockIdx.x * 256 + threadIdx.x;      // o = c*512 + k
    int k = o & 511;
    int c = o >> 9;
    int h = c >> 2, g = c & 3;
    const float* W = (g == 0) ? Wi : (g == 1) ? Wf : (g == 2) ? Wo : Wc;
    wct[o] = (bf16)W[k * 512 + h];
    if (o < 2048) {
        int hh = o >> 2, gg = o & 3;
        const float* bv = (gg == 0) ? bi : (gg == 1) ? bfv : (gg == 2) ? bo : bc;
        bcat[o] = bv[hh];
    }
}

// ---------------- K0c: U pre-swizzled into B-fragment order for phase 2.
__global__ void k0c_uswz(const float* __restrict__ Ui, const float* __restrict__ Uf,
                         const float* __restrict__ Uo, const float* __restrict__ Uc,
                         bf16* __restrict__ usw) {
    int o = blockIdx.x * 256 + threadIdx.x;      // [0, 1048576)
    int e  = o & 7;
    int l  = (o >> 3) & 63;
    int ks = (o >> 9) & 15;
    int nt = (o >> 13) & 1;
    int w  = (o >> 14) & 3;
    int s  = o >> 16;
    int k = ks * 32 + (l >> 4) * 8 + e;
    int col_local = (2 * w + nt) * 16 + (l & 15);
    int h = s * 32 + (col_local >> 2);
    int g = col_local & 3;
    const float* U = (g == 0) ? Ui : (g == 1) ? Uf : (g == 2) ? Uo : Uc;
    usw[o] = (bf16)U[k * 512 + h];
}

// ---------------- K1: xp = x_bf @ W_cat + b_cat, output SWIZZLED for k2.
__launch_bounds__(256, 2)
__global__ void k1_gemm(const bf16* __restrict__ xbf, const bf16* __restrict__ wct,
                        const float* __restrict__ bcat, bf16* __restrict__ xp) {
    __shared__ bf16 As[128 * 40];
    __shared__ bf16 Bs[128 * 40];
    int tid = threadIdx.x;
    int wid = tid >> 6, lane = tid & 63;
    int q = lane >> 4, m = lane & 15;
    int wr = wid >> 1, wc = wid & 1;
    int br = blockIdx.x & 255, bc = blockIdx.x >> 8;

    floatx4 acc[4][4] = {};

    for (int kk = 0; kk < 16; ++kk) {
        #pragma unroll
        for (int cc = 0; cc < 2; ++cc) {
            int ch = tid + cc * 256;
            int row = ch >> 2, part = ch & 3;
            bf16x8 va = *(const bf16x8*)&xbf[(br * 128 + row) * 512 + kk * 32 + part * 8];
            bf16x8 vb = *(const bf16x8*)&wct[(bc * 128 + row) * 512 + kk * 32 + part * 8];
            *(bf16x8*)&As[row * 40 + part * 8] = va;
            *(bf16x8*)&Bs[row * 40 + part * 8] = vb;
        }
        __syncthreads();
        bf16x8 af[4], bfr[4];
        #pragma unroll
        for (int i = 0; i < 4; ++i) {
            af[i]  = *(const bf16x8*)&As[(wr * 64 + i * 16 + m) * 40 + q * 8];
            bfr[i] = *(const bf16x8*)&Bs[(wc * 64 + i * 16 + m) * 40 + q * 8];
        }
        #pragma unroll
        for (int mt = 0; mt < 4; ++mt)
            #pragma unroll
            for (int nt = 0; nt < 4; ++nt)
                acc[mt][nt] = __builtin_amdgcn_mfma_f32_16x16x32_bf16(
                    af[mt], bfr[nt], acc[mt][nt], 0, 0, 0);
        __syncthreads();
    }
    float bias[4];
    #pragma unroll
    for (int nt = 0; nt < 4; ++nt) bias[nt] = bcat[bc * 128 + wc * 64 + nt * 16 + m];
    #pragma unroll
    for (int mt = 0; mt < 4; ++mt) {
        #pragma unroll
        for (int nt = 0; nt < 4; ++nt) {
            u32 p0 = pack_bf16x2(acc[mt][nt][0] + bias[nt], acc[mt][nt][1] + bias[nt]);
            u32 p1 = pack_bf16x2(acc[mt][nt][2] + bias[nt], acc[mt][nt][3] + bias[nt]);
            size_t idx = (((((size_t)(br * 2 + wr) * 4 + mt) * 16 + bc) * 8
                           + wc * 4 + nt) * 64 + lane) * 4;
            uint2 v; v.x = p0; v.y = p1;
            *(uint2*)&xp[idx] = v;
        }
    }
}

// ---------------- K2: persistent recurrence (tagged words, single poll,
// lgkm-only barriers, xp prefetched one step ahead).
// hbuf: u64[2][4][16][256]; word (par,bg,row,pc): hi32 = tag t+1, lo32 =
// packed bf16 col-pair. Store parity t&1, read (t-1)&1.
__launch_bounds__(256, 1)
__global__ void k2_rec(const bf16* __restrict__ xp, const bf16* __restrict__ usw,
                       u64* __restrict__ hbuf, float* __restrict__ out) {
    __shared__ bf16 h_lds[16 * 520];              // A-frag staging, row stride 520
    __shared__ float g_lds[16 * 136];             // [row][col], stride 136 floats
    u32* h32 = (u32*)h_lds;                        // row stride 260 words

    int tid = threadIdx.x;
    int wid = tid >> 6, lane = tid & 63;
    int q = lane >> 4, m = lane & 15;
    int bg = blockIdx.x & 3, s = blockIdx.x >> 2;

    // U B-fragments in registers (one-time, reused all 512 steps)
    bf16x8 bfr[2][16];
    {
        const bf16x8* base = (const bf16x8*)usw;
        #pragma unroll
        for (int nt = 0; nt < 2; ++nt)
            #pragma unroll
            for (int ks = 0; ks < 16; ++ks)
                bfr[nt][ks] = base[(((s * 4 + wid) * 2 + nt) * 16 + ks) * 64 + lane];
    }

    // gate identity == publish identity: row r, units jc, jc+1, pair tid&15
    int r = tid >> 4;
    int jc = (tid & 15) * 2;
    float cs0 = 0.f, cs1 = 0.f;

    // prefetch xp for t=0
    uint2 vx0, vx1;
    {
        size_t b0 = ((((size_t)bg * 16 + s) * 8 + wid * 2) * 64 + lane) * 4;
        vx0 = *(const uint2*)&xp[b0];
        vx1 = *(const uint2*)&xp[b0 + 256];
    }

    for (int t = 0; t < T_STEPS; ++t) {
        floatx4 acc[2];

        if (t > 0) {
            const u64* rb = hbuf + ((size_t)((t - 1) & 1) * 4 + bg) * 4096;
            u32 tg = (u32)t;
            // issue the 16-word coalesced poll first...
            u64 w[16];
            #pragma unroll
            for (int i = 0; i < 16; ++i)
                w[i] = __hip_atomic_load(rb + tid + 256 * i, __ATOMIC_RELAXED,
                                         __HIP_MEMORY_SCOPE_AGENT);
            // ...then unpack last step's xp prefetch (its residual wait
            // overlaps the poll flight)
            acc[0][0] = bf_lo(vx0.x); acc[0][1] = bf_hi(vx0.x);
            acc[0][2] = bf_lo(vx0.y); acc[0][3] = bf_hi(vx0.y);
            acc[1][0] = bf_lo(vx1.x); acc[1][1] = bf_hi(vx1.x);
            acc[1][2] = bf_lo(vx1.y); acc[1][3] = bf_hi(vx1.y);
            for (;;) {
                bool ok = true;
                #pragma unroll
                for (int i = 0; i < 16; ++i) ok &= ((u32)(w[i] >> 32) == tg);
                if (ok) break;
                #pragma unroll
                for (int i = 0; i < 16; ++i)
                    w[i] = __hip_atomic_load(rb + tid + 256 * i, __ATOMIC_RELAXED,
                                             __HIP_MEMORY_SCOPE_AGENT);
            }
            #pragma unroll
            for (int i = 0; i < 16; ++i)
                h32[i * 260 + tid] = (u32)w[i];
            lgkm_barrier();                       // barrier A (LDS-only wait)
            #pragma unroll
            for (int ks = 0; ks < 16; ++ks) {
                bf16x8 af = *(const bf16x8*)&h_lds[m * 520 + ks * 32 + q * 8];
                acc[0] = __builtin_amdgcn_mfma_f32_16x16x32_bf16(af, bfr[0][ks], acc[0], 0, 0, 0);
                acc[1] = __builtin_amdgcn_mfma_f32_16x16x32_bf16(af, bfr[1][ks], acc[1], 0, 0, 0);
            }
        } else {
            acc[0][0] = bf_lo(vx0.x); acc[0][1] = bf_hi(vx0.x);
            acc[0][2] = bf_lo(vx0.y); acc[0][3] = bf_hi(vx0.y);
            acc[1][0] = bf_lo(vx1.x); acc[1][1] = bf_hi(vx1.x);
            acc[1][2] = bf_lo(vx1.y); acc[1][3] = bf_hi(vx1.y);
        }

        // prefetch next step's xp NOW; stays in flight across the lgkm-only
        // barriers, retires off the critical path.
        if (t + 1 < T_STEPS) {
            size_t b0 = (((((size_t)(t + 1) * 4 + bg) * 16 + s) * 8 + wid * 2) * 64 + lane) * 4;
            vx0 = *(const uint2*)&xp[b0];
            vx1 = *(const uint2*)&xp[b0 + 256];
        }

        // scatter g to [row][col] LDS: writes are 2-way banked (free)
        #pragma unroll
        for (int nt = 0; nt < 2; ++nt) {
            int col = (2 * wid + nt) * 16 + m;
            #pragma unroll
            for (int rr = 0; rr < 4; ++rr)
                g_lds[(q * 4 + rr) * 136 + col] = acc[nt][rr];
        }
        lgkm_barrier();                           // barrier B (LDS-only wait)

        // gates: thread (r, jc..jc+1) — two aligned b128 reads
        floatx4 ga = *(const floatx4*)&g_lds[r * 136 + jc * 4];
        floatx4 gb = *(const floatx4*)&g_lds[r * 136 + jc * 4 + 4];
        float h0, h1;
        {
            float ig = 1.f / (1.f + __expf(-ga[0]));
            float fg = 1.f / (1.f + __expf(-ga[1]));
            float og = 1.f / (1.f + __expf(-ga[2]));
            float th = 1.f - 2.f / (__expf(2.f * ga[3]) + 1.f);
            cs0 = fg * cs0 + ig * th;
            h0 = og * (1.f - 2.f / (__expf(2.f * cs0) + 1.f));
        }
        {
            float ig = 1.f / (1.f + __expf(-gb[0]));
            float fg = 1.f / (1.f + __expf(-gb[1]));
            float og = 1.f / (1.f + __expf(-gb[2]));
            float th = 1.f - 2.f / (__expf(2.f * gb[3]) + 1.f);
            cs1 = fg * cs1 + ig * th;
            h1 = og * (1.f - 2.f / (__expf(2.f * cs1) + 1.f));
        }
        // coalesced tagged publish (4 x 128B segments per wave)
        u64 word = ((u64)(u32)(t + 1) << 32) | (u64)pack_bf16x2(h0, h1);
        __hip_atomic_store(hbuf + (((size_t)(t & 1) * 4 + bg) * 16 + r) * 256
                                + s * 16 + (tid & 15),
                           word, __ATOMIC_RELAXED, __HIP_MEMORY_SCOPE_AGENT);
        if (t == T_STEPS - 1) {
            out[(bg * 16 + r) * 512 + s * 32 + jc]     = h0;
            out[(bg * 16 + r) * 512 + s * 32 + jc + 1] = h1;
        }
    }
}

// ---------------------------------------------------------------------------
extern "C" void kernel_launch(void* const* d_in, const int* in_sizes, int n_in,
                              void* d_out, int out_size, void* d_ws, size_t ws_size,
                              hipStream_t stream) {
    const float* inp = (const float*)d_in[0];
    const float* Wi  = (const float*)d_in[1];
    const float* Wf  = (const float*)d_in[2];
    const float* Wo  = (const float*)d_in[3];
    const float* Wc  = (const float*)d_in[4];
    const float* Ui  = (const float*)d_in[5];
    const float* Uf  = (const float*)d_in[6];
    const float* Uo  = (const float*)d_in[7];
    const float* Uc  = (const float*)d_in[8];
    const float* bi  = (const float*)d_in[9];
    const float* bfv = (const float*)d_in[10];
    const float* bo  = (const float*)d_in[11];
    const float* bc  = (const float*)d_in[12];

    char* ws = (char*)d_ws;
    bf16*  xp    = (bf16*)(ws + XP_OFF);
    bf16*  xbf   = (bf16*)(ws + XBF_OFF);
    bf16*  wct   = (bf16*)(ws + WCT_OFF);
    bf16*  usw   = (bf16*)(ws + USW_OFF);
    float* bcat  = (float*)(ws + BCAT_OFF);
    u64*   hbuf  = (u64*)(ws + HBUF_OFF);

    k0a_convert<<<65536, 256, 0, stream>>>(inp, xbf);
    k0b_wcat<<<4096, 256, 0, stream>>>(Wi, Wf, Wo, Wc, bi, bfv, bo, bc, wct, bcat);
    k0c_uswz<<<4096, 256, 0, stream>>>(Ui, Uf, Uo, Uc, usw);
    k1_gemm<<<4096, 256, 0, stream>>>(xbf, wct, bcat, xp);
    k2_rec<<<64, 256, 0, stream>>>(xp, usw, hbuf, (float*)d_out);
}

// Round 9
// 1421.233 us; speedup vs baseline: 1.1339x; 1.1339x over previous
//
#include <hip/hip_runtime.h>
#include <hip/hip_bf16.h>
#include <cstdint>

// ---------------------------------------------------------------------------
// LSTM  B=64 T=512 I=512 H=512
// Phase 0: convert/transpose inputs -> bf16, W_cat^T bf16, b_cat f32,
//          U pre-swizzled into MFMA B-fragment order.
// Phase 1: x_proj GEMM bf16 MFMA, bias folded, output consumer-swizzled.
// Phase 2: persistent recurrence, 64 WGs = 4 batch-groups x 16 hidden-slices.
//          U slice in registers. h exchanged via TAGGED u64 words (hi32 = tag
//          t+1, lo32 = packed bf16 col-pair), relaxed agent atomics (data IS
//          the flag). Single 16-word coalesced poll. Barriers are LGKM-only
//          (global ops stay in flight across them). xp prefetched one step
//          ahead into registers (retires off the serial path).
//          NEW vs R8: calibrated ~512cyc s_sleep BEFORE issuing the first
//          poll sample. Evidence across R4-R8: a sample issued immediately
//          after publish is always stale (other producers' stores not yet
//          MALL-visible) and costs a full extra round trip; R4's best time
//          came from an accidental ~1000cyc delay (xp HBM wait). The sleep
//          reproduces that delay at half the cost, with xp prefetched.
// Column convention: c = h_unit*4 + gate   (gate: 0=i,1=f,2=o,3=c)
// ---------------------------------------------------------------------------

typedef __bf16 bf16;
typedef __bf16 bf16x8 __attribute__((ext_vector_type(8)));
typedef float floatx4 __attribute__((ext_vector_type(4)));
typedef uint64_t u64;
typedef uint32_t u32;

#define T_STEPS 512

// ws layout (bytes)
#define XP_OFF     0ull                        // bf16 [T*B*2048] swizzled = 128 MB
#define XBF_OFF    134217728ull                // bf16 [T*B][512]   = 32 MB
#define WCT_OFF    167772160ull                // bf16 [2048][512]  = 2 MB
#define USW_OFF    169869312ull                // bf16 swizzled U B-frags = 2 MB
#define BCAT_OFF   171966464ull                // f32  [2048]
#define HBUF_OFF   171974656ull                // u64 [2][4][16][256] = 256 KB

__device__ inline u32 pack_bf16x2(float a, float b) {
    union { __bf16 h[2]; u32 u; } cv;
    cv.h[0] = (__bf16)a; cv.h[1] = (__bf16)b;
    return cv.u;
}
__device__ inline float bf_lo(u32 w) { return __builtin_bit_cast(float, w << 16); }
__device__ inline float bf_hi(u32 w) { return __builtin_bit_cast(float, w & 0xffff0000u); }

// barrier that waits only LDS (lgkmcnt(0)); global loads/stores stay in flight.
// simm16: vmcnt lo[3:0]=0xF, expcnt[6:4]=7, lgkmcnt[11:8]=0, vmcnt hi[15:14]=3
__device__ inline void lgkm_barrier() {
    __atomic_signal_fence(__ATOMIC_SEQ_CST);
    __builtin_amdgcn_s_waitcnt(0xc07f);
    __builtin_amdgcn_s_barrier();
    __atomic_signal_fence(__ATOMIC_SEQ_CST);
}

// ---------------- K0a: inputs f32 [B][T][I] -> x_bf bf16 in row order (t*64+b)
__global__ void k0a_convert(const float* __restrict__ in, bf16* __restrict__ xbf) {
    int o = blockIdx.x * 256 + threadIdx.x;
    int k = o & 511;
    int r = o >> 9;
    int t = r >> 6, b = r & 63;
    xbf[o] = (bf16)in[(b * 512 + t) * 512 + k];
}

// ---------------- K0b: W_cat^T[c][k] bf16 (c = h*4+gate) and b_cat f32
__global__ void k0b_wcat(const float* __restrict__ Wi, const float* __restrict__ Wf,
                         const float* __restrict__ Wo, const float* __restrict__ Wc,
                         const float* __restrict__ bi, const float* __restrict__ bfv,
                         const float* __restrict__ bo, const float* __restrict__ bc,
                         bf16* __restrict__ wct, float* __restrict__ bcat) {
    int o = blockIdx.x * 256 + threadIdx.x;      // o = c*512 + k
    int k = o & 511;
    int c = o >> 9;
    int h = c >> 2, g = c & 3;
    const float* W = (g == 0) ? Wi : (g == 1) ? Wf : (g == 2) ? Wo : Wc;
    wct[o] = (bf16)W[k * 512 + h];
    if (o < 2048) {
        int hh = o >> 2, gg = o & 3;
        const float* bv = (gg == 0) ? bi : (gg == 1) ? bfv : (gg == 2) ? bo : bc;
        bcat[o] = bv[hh];
    }
}

// ---------------- K0c: U pre-swizzled into B-fragment order for phase 2.
__global__ void k0c_uswz(const float* __restrict__ Ui, const float* __restrict__ Uf,
                         const float* __restrict__ Uo, const float* __restrict__ Uc,
                         bf16* __restrict__ usw) {
    int o = blockIdx.x * 256 + threadIdx.x;      // [0, 1048576)
    int e  = o & 7;
    int l  = (o >> 3) & 63;
    int ks = (o >> 9) & 15;
    int nt = (o >> 13) & 1;
    int w  = (o >> 14) & 3;
    int s  = o >> 16;
    int k = ks * 32 + (l >> 4) * 8 + e;
    int col_local = (2 * w + nt) * 16 + (l & 15);
    int h = s * 32 + (col_local >> 2);
    int g = col_local & 3;
    const float* U = (g == 0) ? Ui : (g == 1) ? Uf : (g == 2) ? Uo : Uc;
    usw[o] = (bf16)U[k * 512 + h];
}

// ---------------- K1: xp = x_bf @ W_cat + b_cat, output SWIZZLED for k2.
__launch_bounds__(256, 2)
__global__ void k1_gemm(const bf16* __restrict__ xbf, const bf16* __restrict__ wct,
                        const float* __restrict__ bcat, bf16* __restrict__ xp) {
    __shared__ bf16 As[128 * 40];
    __shared__ bf16 Bs[128 * 40];
    int tid = threadIdx.x;
    int wid = tid >> 6, lane = tid & 63;
    int q = lane >> 4, m = lane & 15;
    int wr = wid >> 1, wc = wid & 1;
    int br = blockIdx.x & 255, bc = blockIdx.x >> 8;

    floatx4 acc[4][4] = {};

    for (int kk = 0; kk < 16; ++kk) {
        #pragma unroll
        for (int cc = 0; cc < 2; ++cc) {
            int ch = tid + cc * 256;
            int row = ch >> 2, part = ch & 3;
            bf16x8 va = *(const bf16x8*)&xbf[(br * 128 + row) * 512 + kk * 32 + part * 8];
            bf16x8 vb = *(const bf16x8*)&wct[(bc * 128 + row) * 512 + kk * 32 + part * 8];
            *(bf16x8*)&As[row * 40 + part * 8] = va;
            *(bf16x8*)&Bs[row * 40 + part * 8] = vb;
        }
        __syncthreads();
        bf16x8 af[4], bfr[4];
        #pragma unroll
        for (int i = 0; i < 4; ++i) {
            af[i]  = *(const bf16x8*)&As[(wr * 64 + i * 16 + m) * 40 + q * 8];
            bfr[i] = *(const bf16x8*)&Bs[(wc * 64 + i * 16 + m) * 40 + q * 8];
        }
        #pragma unroll
        for (int mt = 0; mt < 4; ++mt)
            #pragma unroll
            for (int nt = 0; nt < 4; ++nt)
                acc[mt][nt] = __builtin_amdgcn_mfma_f32_16x16x32_bf16(
                    af[mt], bfr[nt], acc[mt][nt], 0, 0, 0);
        __syncthreads();
    }
    float bias[4];
    #pragma unroll
    for (int nt = 0; nt < 4; ++nt) bias[nt] = bcat[bc * 128 + wc * 64 + nt * 16 + m];
    #pragma unroll
    for (int mt = 0; mt < 4; ++mt) {
        #pragma unroll
        for (int nt = 0; nt < 4; ++nt) {
            u32 p0 = pack_bf16x2(acc[mt][nt][0] + bias[nt], acc[mt][nt][1] + bias[nt]);
            u32 p1 = pack_bf16x2(acc[mt][nt][2] + bias[nt], acc[mt][nt][3] + bias[nt]);
            size_t idx = (((((size_t)(br * 2 + wr) * 4 + mt) * 16 + bc) * 8
                           + wc * 4 + nt) * 64 + lane) * 4;
            uint2 v; v.x = p0; v.y = p1;
            *(uint2*)&xp[idx] = v;
        }
    }
}

// ---------------- K2: persistent recurrence (tagged words, single poll with
// calibrated pre-poll delay, lgkm-only barriers, xp prefetched one step ahead).
// hbuf: u64[2][4][16][256]; word (par,bg,row,pc): hi32 = tag t+1, lo32 =
// packed bf16 col-pair. Store parity t&1, read (t-1)&1.
__launch_bounds__(256, 1)
__global__ void k2_rec(const bf16* __restrict__ xp, const bf16* __restrict__ usw,
                       u64* __restrict__ hbuf, float* __restrict__ out) {
    __shared__ bf16 h_lds[16 * 520];              // A-frag staging, row stride 520
    __shared__ float g_lds[16 * 136];             // [row][col], stride 136 floats
    u32* h32 = (u32*)h_lds;                        // row stride 260 words

    int tid = threadIdx.x;
    int wid = tid >> 6, lane = tid & 63;
    int q = lane >> 4, m = lane & 15;
    int bg = blockIdx.x & 3, s = blockIdx.x >> 2;

    // U B-fragments in registers (one-time, reused all 512 steps)
    bf16x8 bfr[2][16];
    {
        const bf16x8* base = (const bf16x8*)usw;
        #pragma unroll
        for (int nt = 0; nt < 2; ++nt)
            #pragma unroll
            for (int ks = 0; ks < 16; ++ks)
                bfr[nt][ks] = base[(((s * 4 + wid) * 2 + nt) * 16 + ks) * 64 + lane];
    }

    // gate identity == publish identity: row r, units jc, jc+1, pair tid&15
    int r = tid >> 4;
    int jc = (tid & 15) * 2;
    float cs0 = 0.f, cs1 = 0.f;

    // prefetch xp for t=0
    uint2 vx0, vx1;
    {
        size_t b0 = ((((size_t)bg * 16 + s) * 8 + wid * 2) * 64 + lane) * 4;
        vx0 = *(const uint2*)&xp[b0];
        vx1 = *(const uint2*)&xp[b0 + 256];
    }

    for (int t = 0; t < T_STEPS; ++t) {
        floatx4 acc[2];

        // unpack the xp prefetch (issued last step; retired by now)
        acc[0][0] = bf_lo(vx0.x); acc[0][1] = bf_hi(vx0.x);
        acc[0][2] = bf_lo(vx0.y); acc[0][3] = bf_hi(vx0.y);
        acc[1][0] = bf_lo(vx1.x); acc[1][1] = bf_hi(vx1.x);
        acc[1][2] = bf_lo(vx1.y); acc[1][3] = bf_hi(vx1.y);

        if (t > 0) {
            // calibrated pre-poll delay (~512 cyc): lets the other 15
            // producers' stores reach the MALL so the FIRST sample succeeds.
            // (R4-R8 evidence: zero delay => guaranteed stale => +1 full
            // round trip per step.)
            __atomic_signal_fence(__ATOMIC_SEQ_CST);
            __builtin_amdgcn_s_sleep(8);
            __atomic_signal_fence(__ATOMIC_SEQ_CST);

            const u64* rb = hbuf + ((size_t)((t - 1) & 1) * 4 + bg) * 4096;
            u32 tg = (u32)t;
            u64 w[16];
            #pragma unroll
            for (int i = 0; i < 16; ++i)
                w[i] = __hip_atomic_load(rb + tid + 256 * i, __ATOMIC_RELAXED,
                                         __HIP_MEMORY_SCOPE_AGENT);
            for (;;) {
                bool ok = true;
                #pragma unroll
                for (int i = 0; i < 16; ++i) ok &= ((u32)(w[i] >> 32) == tg);
                if (ok) break;
                #pragma unroll
                for (int i = 0; i < 16; ++i)
                    w[i] = __hip_atomic_load(rb + tid + 256 * i, __ATOMIC_RELAXED,
                                             __HIP_MEMORY_SCOPE_AGENT);
            }
            #pragma unroll
            for (int i = 0; i < 16; ++i)
                h32[i * 260 + tid] = (u32)w[i];
            lgkm_barrier();                       // barrier A (LDS-only wait)
            #pragma unroll
            for (int ks = 0; ks < 16; ++ks) {
                bf16x8 af = *(const bf16x8*)&h_lds[m * 520 + ks * 32 + q * 8];
                acc[0] = __builtin_amdgcn_mfma_f32_16x16x32_bf16(af, bfr[0][ks], acc[0], 0, 0, 0);
                acc[1] = __builtin_amdgcn_mfma_f32_16x16x32_bf16(af, bfr[1][ks], acc[1], 0, 0, 0);
            }
        }

        // prefetch next step's xp NOW; survives the lgkm-only barriers and
        // retires off the critical path.
        if (t + 1 < T_STEPS) {
            size_t b0 = (((((size_t)(t + 1) * 4 + bg) * 16 + s) * 8 + wid * 2) * 64 + lane) * 4;
            vx0 = *(const uint2*)&xp[b0];
            vx1 = *(const uint2*)&xp[b0 + 256];
        }

        // scatter g to [row][col] LDS: writes are 2-way banked (free)
        #pragma unroll
        for (int nt = 0; nt < 2; ++nt) {
            int col = (2 * wid + nt) * 16 + m;
            #pragma unroll
            for (int rr = 0; rr < 4; ++rr)
                g_lds[(q * 4 + rr) * 136 + col] = acc[nt][rr];
        }
        lgkm_barrier();                           // barrier B (LDS-only wait)

        // gates: thread (r, jc..jc+1) — two aligned b128 reads
        floatx4 ga = *(const floatx4*)&g_lds[r * 136 + jc * 4];
        floatx4 gb = *(const floatx4*)&g_lds[r * 136 + jc * 4 + 4];
        float h0, h1;
        {
            float ig = 1.f / (1.f + __expf(-ga[0]));
            float fg = 1.f / (1.f + __expf(-ga[1]));
            float og = 1.f / (1.f + __expf(-ga[2]));
            float th = 1.f - 2.f / (__expf(2.f * ga[3]) + 1.f);
            cs0 = fg * cs0 + ig * th;
            h0 = og * (1.f - 2.f / (__expf(2.f * cs0) + 1.f));
        }
        {
            float ig = 1.f / (1.f + __expf(-gb[0]));
            float fg = 1.f / (1.f + __expf(-gb[1]));
            float og = 1.f / (1.f + __expf(-gb[2]));
            float th = 1.f - 2.f / (__expf(2.f * gb[3]) + 1.f);
            cs1 = fg * cs1 + ig * th;
            h1 = og * (1.f - 2.f / (__expf(2.f * cs1) + 1.f));
        }
        // coalesced tagged publish (4 x 128B segments per wave)
        u64 word = ((u64)(u32)(t + 1) << 32) | (u64)pack_bf16x2(h0, h1);
        __hip_atomic_store(hbuf + (((size_t)(t & 1) * 4 + bg) * 16 + r) * 256
                                + s * 16 + (tid & 15),
                           word, __ATOMIC_RELAXED, __HIP_MEMORY_SCOPE_AGENT);
        if (t == T_STEPS - 1) {
            out[(bg * 16 + r) * 512 + s * 32 + jc]     = h0;
            out[(bg * 16 + r) * 512 + s * 32 + jc + 1] = h1;
        }
    }
}

// ---------------------------------------------------------------------------
extern "C" void kernel_launch(void* const* d_in, const int* in_sizes, int n_in,
                              void* d_out, int out_size, void* d_ws, size_t ws_size,
                              hipStream_t stream) {
    const float* inp = (const float*)d_in[0];
    const float* Wi  = (const float*)d_in[1];
    const float* Wf  = (const float*)d_in[2];
    const float* Wo  = (const float*)d_in[3];
    const float* Wc  = (const float*)d_in[4];
    const float* Ui  = (const float*)d_in[5];
    const float* Uf  = (const float*)d_in[6];
    const float* Uo  = (const float*)d_in[7];
    const float* Uc  = (const float*)d_in[8];
    const float* bi  = (const float*)d_in[9];
    const float* bfv = (const float*)d_in[10];
    const float* bo  = (const float*)d_in[11];
    const float* bc  = (const float*)d_in[12];

    char* ws = (char*)d_ws;
    bf16*  xp    = (bf16*)(ws + XP_OFF);
    bf16*  xbf   = (bf16*)(ws + XBF_OFF);
    bf16*  wct   = (bf16*)(ws + WCT_OFF);
    bf16*  usw   = (bf16*)(ws + USW_OFF);
    float* bcat  = (float*)(ws + BCAT_OFF);
    u64*   hbuf  = (u64*)(ws + HBUF_OFF);

    k0a_convert<<<65536, 256, 0, stream>>>(inp, xbf);
    k0b_wcat<<<4096, 256, 0, stream>>>(Wi, Wf, Wo, Wc, bi, bfv, bo, bc, wct, bcat);
    k0c_uswz<<<4096, 256, 0, stream>>>(Ui, Uf, Uo, Uc, usw);
    k1_gemm<<<4096, 256, 0, stream>>>(xbf, wct, bcat, xp);
    k2_rec<<<64, 256, 0, stream>>>(xp, usw, hbuf, (float*)d_out);
}